// Round 2
// baseline (393.658 us; speedup 1.0000x reference)
//
#include <hip/hip_runtime.h>

// PixCorr: per-row Pearson correlation of preds vs targets, mean over rows.
// preds/targets: fp32, N=256 rows, D=3*256*256=196608 elements per row.
// Memory-bound: 402.7 MB streamed once. R1 was latency-bound (16 waves/CU,
// vmcnt(0) drain per 2 loads). R2: 16 chunks/row -> 4096 blocks x 256 thr
// (32 waves/CU) + unroll x4 batched loads for MLP. Deterministic two-stage
// reduction through d_ws (no atomics, no memset needed).

constexpr int NROWS  = 256;
constexpr int D      = 3 * 256 * 256;   // 196608 floats per row
constexpr int D4     = D / 4;           // 49152 float4 per row
constexpr int CHUNKS = 16;              // chunks per row
constexpr int TPB1   = 256;             // 4 waves per block
constexpr int C4     = D4 / CHUNKS;     // 3072 float4 per chunk
constexpr int ITERS  = C4 / TPB1;       // 12 float4 per thread
constexpr double EPS = 1e-6;

// ws layout: partials[4096][5] doubles = 160 KiB
__global__ __launch_bounds__(TPB1) void partial_kernel(
        const float4* __restrict__ preds,
        const float4* __restrict__ targets,
        double* __restrict__ partials)
{
    const int  blk   = blockIdx.x;
    const int  row   = blk / CHUNKS;
    const int  chunk = blk % CHUNKS;
    const int  tid   = threadIdx.x;
    const long base  = (long)row * D4 + (long)chunk * C4 + tid;

    double sZ = 0.0, sB = 0.0, sZZ = 0.0, sBB = 0.0, sZB = 0.0;

    // Unroll x4: issue 8 dwordx4 loads before consuming -> deep MLP.
    #pragma unroll
    for (int it = 0; it < ITERS; it += 4) {
        float4 z4[4], b4[4];
        #pragma unroll
        for (int u = 0; u < 4; ++u) {
            const long idx = base + (long)(it + u) * TPB1;
            b4[u] = preds[idx];    // B = preds
            z4[u] = targets[idx];  // Z = targets
        }
        #pragma unroll
        for (int u = 0; u < 4; ++u) {
            double z, b;
            z = (double)z4[u].x; b = (double)b4[u].x;
            sZ += z; sB += b; sZZ = fma(z,z,sZZ); sBB = fma(b,b,sBB); sZB = fma(z,b,sZB);
            z = (double)z4[u].y; b = (double)b4[u].y;
            sZ += z; sB += b; sZZ = fma(z,z,sZZ); sBB = fma(b,b,sBB); sZB = fma(z,b,sZB);
            z = (double)z4[u].z; b = (double)b4[u].z;
            sZ += z; sB += b; sZZ = fma(z,z,sZZ); sBB = fma(b,b,sBB); sZB = fma(z,b,sZB);
            z = (double)z4[u].w; b = (double)b4[u].w;
            sZ += z; sB += b; sZZ = fma(z,z,sZZ); sBB = fma(b,b,sBB); sZB = fma(z,b,sZB);
        }
    }

    // Wave (64-lane) shuffle reduction.
    #pragma unroll
    for (int off = 32; off > 0; off >>= 1) {
        sZ  += __shfl_down(sZ,  off);
        sB  += __shfl_down(sB,  off);
        sZZ += __shfl_down(sZZ, off);
        sBB += __shfl_down(sBB, off);
        sZB += __shfl_down(sZB, off);
    }

    constexpr int NWAVES = TPB1 / 64;
    __shared__ double sm[5][NWAVES];
    const int wave = tid >> 6;
    const int lane = tid & 63;
    if (lane == 0) {
        sm[0][wave] = sZ;  sm[1][wave] = sB;
        sm[2][wave] = sZZ; sm[3][wave] = sBB;
        sm[4][wave] = sZB;
    }
    __syncthreads();

    if (tid == 0) {
        double t[5];
        #pragma unroll
        for (int k = 0; k < 5; ++k) {
            double acc = 0.0;
            #pragma unroll
            for (int w = 0; w < NWAVES; ++w) acc += sm[k][w];
            t[k] = acc;
        }
        double* out = partials + (long)blk * 5;
        #pragma unroll
        for (int k = 0; k < 5; ++k) out[k] = t[k];
    }
}

// One block, 256 threads: thread r reduces its row's 16 chunk-partials,
// computes corr_r, then block-reduces the mean.
__global__ __launch_bounds__(NROWS) void finish_kernel(
        const double* __restrict__ partials, float* __restrict__ out)
{
    const int r = threadIdx.x;
    double tZ = 0, tB = 0, tZZ = 0, tBB = 0, tZB = 0;
    const double* p = partials + (long)r * CHUNKS * 5;
    #pragma unroll
    for (int c = 0; c < CHUNKS; ++c) {
        tZ  += p[c * 5 + 0];
        tB  += p[c * 5 + 1];
        tZZ += p[c * 5 + 2];
        tBB += p[c * 5 + 3];
        tZB += p[c * 5 + 4];
    }
    const double invD = 1.0 / (double)D;
    const double num  = tZB - tZ * tB * invD;
    const double varZ = fmax(tZZ - tZ * tZ * invD, 0.0);
    const double varB = fmax(tBB - tB * tB * invD, 0.0);
    const double den  = sqrt(varZ) * sqrt(varB) + EPS;
    double v = num / den;

    #pragma unroll
    for (int off = 32; off > 0; off >>= 1) v += __shfl_down(v, off);

    __shared__ double sm[NROWS / 64];
    const int wave = r >> 6;
    const int lane = r & 63;
    if (lane == 0) sm[wave] = v;
    __syncthreads();
    if (r == 0) {
        double t = 0.0;
        #pragma unroll
        for (int w = 0; w < NROWS / 64; ++w) t += sm[w];
        out[0] = (float)(t / (double)NROWS);
    }
}

extern "C" void kernel_launch(void* const* d_in, const int* in_sizes, int n_in,
                              void* d_out, int out_size, void* d_ws, size_t ws_size,
                              hipStream_t stream) {
    const float4* preds   = (const float4*)d_in[0];
    const float4* targets = (const float4*)d_in[1];
    double* partials = (double*)d_ws;   // 4096 * 5 doubles = 160 KiB
    float*  out      = (float*)d_out;

    hipLaunchKernelGGL(partial_kernel, dim3(NROWS * CHUNKS), dim3(TPB1), 0, stream,
                       preds, targets, partials);
    hipLaunchKernelGGL(finish_kernel, dim3(1), dim3(NROWS), 0, stream,
                       partials, out);
}

// Round 3
// 382.626 us; speedup vs baseline: 1.0288x; 1.0288x over previous
//
#include <hip/hip_runtime.h>

// PixCorr: per-row Pearson correlation of preds vs targets, mean over rows.
// fp32, N=256 rows, D=3*256*256=196608 per row; 402.7 MB streamed once.
// R1/R2 both plateaued at 134us (~3.0 TB/s effective read) regardless of
// TLP/MLP shape. FETCH ~= sizeof(preds): targets sit in L3 (restore copy
// wrote them last), preds stream from HBM. R3 theory: preds' cache
// allocation thrashes L3/L2 and evicts targets mid-kernel. Fix: preds via
// nontemporal loads (nt, no L2/L3 allocation); targets cached. Plus forced
// 6-pair load batches for per-wave MLP.

typedef float f4 __attribute__((ext_vector_type(4)));

constexpr int NROWS  = 256;
constexpr int D      = 3 * 256 * 256;   // 196608 floats per row
constexpr int D4     = D / 4;           // 49152 float4 per row
constexpr int CHUNKS = 16;              // chunks per row
constexpr int TPB1   = 256;             // 4 waves per block
constexpr int C4     = D4 / CHUNKS;     // 3072 float4 per chunk
constexpr int ITERS  = C4 / TPB1;       // 12 float4 per thread
constexpr int BATCH  = 6;               // 6 z + 6 b loads in flight
constexpr double EPS = 1e-6;

__global__ __launch_bounds__(TPB1) void partial_kernel(
        const f4* __restrict__ preds,
        const f4* __restrict__ targets,
        double* __restrict__ partials)
{
    const int  blk   = blockIdx.x;
    const int  row   = blk / CHUNKS;
    const int  chunk = blk % CHUNKS;
    const int  tid   = threadIdx.x;
    const long base  = (long)row * D4 + (long)chunk * C4 + tid;

    double sZ = 0.0, sB = 0.0, sZZ = 0.0, sBB = 0.0, sZB = 0.0;

    #pragma unroll
    for (int it = 0; it < ITERS; it += BATCH) {
        f4 z4[BATCH], b4[BATCH];
        // Issue all 2*BATCH loads before any use.
        #pragma unroll
        for (int u = 0; u < BATCH; ++u) {
            const long idx = base + (long)(it + u) * TPB1;
            b4[u] = __builtin_nontemporal_load(&preds[idx]);  // B = preds, nt
            z4[u] = targets[idx];                             // Z = targets, cached
        }
        #pragma unroll
        for (int u = 0; u < BATCH; ++u) {
            double z, b;
            z = (double)z4[u].x; b = (double)b4[u].x;
            sZ += z; sB += b; sZZ = fma(z,z,sZZ); sBB = fma(b,b,sBB); sZB = fma(z,b,sZB);
            z = (double)z4[u].y; b = (double)b4[u].y;
            sZ += z; sB += b; sZZ = fma(z,z,sZZ); sBB = fma(b,b,sBB); sZB = fma(z,b,sZB);
            z = (double)z4[u].z; b = (double)b4[u].z;
            sZ += z; sB += b; sZZ = fma(z,z,sZZ); sBB = fma(b,b,sBB); sZB = fma(z,b,sZB);
            z = (double)z4[u].w; b = (double)b4[u].w;
            sZ += z; sB += b; sZZ = fma(z,z,sZZ); sBB = fma(b,b,sBB); sZB = fma(z,b,sZB);
        }
    }

    // Wave (64-lane) shuffle reduction.
    #pragma unroll
    for (int off = 32; off > 0; off >>= 1) {
        sZ  += __shfl_down(sZ,  off);
        sB  += __shfl_down(sB,  off);
        sZZ += __shfl_down(sZZ, off);
        sBB += __shfl_down(sBB, off);
        sZB += __shfl_down(sZB, off);
    }

    constexpr int NWAVES = TPB1 / 64;
    __shared__ double sm[5][NWAVES];
    const int wave = tid >> 6;
    const int lane = tid & 63;
    if (lane == 0) {
        sm[0][wave] = sZ;  sm[1][wave] = sB;
        sm[2][wave] = sZZ; sm[3][wave] = sBB;
        sm[4][wave] = sZB;
    }
    __syncthreads();

    if (tid == 0) {
        double* out = partials + (long)blk * 5;
        #pragma unroll
        for (int k = 0; k < 5; ++k) {
            double acc = 0.0;
            #pragma unroll
            for (int w = 0; w < NWAVES; ++w) acc += sm[k][w];
            out[k] = acc;
        }
    }
}

// One block, 256 threads: thread r reduces its row's 16 chunk-partials,
// computes corr_r, then block-reduces the mean.
__global__ __launch_bounds__(NROWS) void finish_kernel(
        const double* __restrict__ partials, float* __restrict__ out)
{
    const int r = threadIdx.x;
    double tZ = 0, tB = 0, tZZ = 0, tBB = 0, tZB = 0;
    const double* p = partials + (long)r * CHUNKS * 5;
    #pragma unroll
    for (int c = 0; c < CHUNKS; ++c) {
        tZ  += p[c * 5 + 0];
        tB  += p[c * 5 + 1];
        tZZ += p[c * 5 + 2];
        tBB += p[c * 5 + 3];
        tZB += p[c * 5 + 4];
    }
    const double invD = 1.0 / (double)D;
    const double num  = tZB - tZ * tB * invD;
    const double varZ = fmax(tZZ - tZ * tZ * invD, 0.0);
    const double varB = fmax(tBB - tB * tB * invD, 0.0);
    const double den  = sqrt(varZ) * sqrt(varB) + EPS;
    double v = num / den;

    #pragma unroll
    for (int off = 32; off > 0; off >>= 1) v += __shfl_down(v, off);

    __shared__ double sm[NROWS / 64];
    const int wave = r >> 6;
    const int lane = r & 63;
    if (lane == 0) sm[wave] = v;
    __syncthreads();
    if (r == 0) {
        double t = 0.0;
        #pragma unroll
        for (int w = 0; w < NROWS / 64; ++w) t += sm[w];
        out[0] = (float)(t / (double)NROWS);
    }
}

extern "C" void kernel_launch(void* const* d_in, const int* in_sizes, int n_in,
                              void* d_out, int out_size, void* d_ws, size_t ws_size,
                              hipStream_t stream) {
    const f4* preds   = (const f4*)d_in[0];
    const f4* targets = (const f4*)d_in[1];
    double* partials = (double*)d_ws;   // 4096 * 5 doubles = 160 KiB
    float*  out      = (float*)d_out;

    hipLaunchKernelGGL(partial_kernel, dim3(NROWS * CHUNKS), dim3(TPB1), 0, stream,
                       preds, targets, partials);
    hipLaunchKernelGGL(finish_kernel, dim3(1), dim3(NROWS), 0, stream,
                       partials, out);
}

// Round 4
// 371.505 us; speedup vs baseline: 1.0596x; 1.0299x over previous
//
#include <hip/hip_runtime.h>

// PixCorr: per-row Pearson correlation of preds vs targets, mean over rows.
// fp32, N=256 rows, D=3*256*256=196608 per row; 402.7 MB streamed once.
// R3: nt on preds broke the 134us plateau (kernel now <117us; top-5 is all
// harness fillBuffer resets at 6.9 TB/s). R4: nt on BOTH streams (stop L2/L3
// thrash entirely; targets still L3-hit from restore copy), 32 chunks/row ->
// 8192 short-lived blocks, one 6-pair batch per thread (12 dwordx4 in flight,
// consumed once) -> pipelining via wave turnover. Floor: ~60us at 6.9 TB/s.

typedef float f4 __attribute__((ext_vector_type(4)));

constexpr int NROWS  = 256;
constexpr int D      = 3 * 256 * 256;   // 196608 floats per row
constexpr int D4     = D / 4;           // 49152 float4 per row
constexpr int CHUNKS = 32;              // chunks per row
constexpr int TPB1   = 256;             // 4 waves per block
constexpr int C4     = D4 / CHUNKS;     // 1536 float4 per chunk
constexpr int BATCH  = C4 / TPB1;       // 6 float4 pairs per thread (one batch)
constexpr double EPS = 1e-6;

// ws layout: partials[8192][5] doubles = 320 KiB
__global__ __launch_bounds__(TPB1) void partial_kernel(
        const f4* __restrict__ preds,
        const f4* __restrict__ targets,
        double* __restrict__ partials)
{
    const int  blk   = blockIdx.x;
    const int  row   = blk / CHUNKS;
    const int  chunk = blk % CHUNKS;
    const int  tid   = threadIdx.x;
    const long base  = (long)row * D4 + (long)chunk * C4 + tid;

    // Issue all 12 loads back-to-back, then consume once.
    f4 z4[BATCH], b4[BATCH];
    #pragma unroll
    for (int u = 0; u < BATCH; ++u) {
        const long idx = base + (long)u * TPB1;
        b4[u] = __builtin_nontemporal_load(&preds[idx]);    // B = preds
        z4[u] = __builtin_nontemporal_load(&targets[idx]);  // Z = targets
    }

    double sZ = 0.0, sB = 0.0, sZZ = 0.0, sBB = 0.0, sZB = 0.0;
    #pragma unroll
    for (int u = 0; u < BATCH; ++u) {
        double z, b;
        z = (double)z4[u].x; b = (double)b4[u].x;
        sZ += z; sB += b; sZZ = fma(z,z,sZZ); sBB = fma(b,b,sBB); sZB = fma(z,b,sZB);
        z = (double)z4[u].y; b = (double)b4[u].y;
        sZ += z; sB += b; sZZ = fma(z,z,sZZ); sBB = fma(b,b,sBB); sZB = fma(z,b,sZB);
        z = (double)z4[u].z; b = (double)b4[u].z;
        sZ += z; sB += b; sZZ = fma(z,z,sZZ); sBB = fma(b,b,sBB); sZB = fma(z,b,sZB);
        z = (double)z4[u].w; b = (double)b4[u].w;
        sZ += z; sB += b; sZZ = fma(z,z,sZZ); sBB = fma(b,b,sBB); sZB = fma(z,b,sZB);
    }

    // Wave (64-lane) shuffle reduction.
    #pragma unroll
    for (int off = 32; off > 0; off >>= 1) {
        sZ  += __shfl_down(sZ,  off);
        sB  += __shfl_down(sB,  off);
        sZZ += __shfl_down(sZZ, off);
        sBB += __shfl_down(sBB, off);
        sZB += __shfl_down(sZB, off);
    }

    constexpr int NWAVES = TPB1 / 64;
    __shared__ double sm[5][NWAVES];
    const int wave = tid >> 6;
    const int lane = tid & 63;
    if (lane == 0) {
        sm[0][wave] = sZ;  sm[1][wave] = sB;
        sm[2][wave] = sZZ; sm[3][wave] = sBB;
        sm[4][wave] = sZB;
    }
    __syncthreads();

    if (tid == 0) {
        double* out = partials + (long)blk * 5;
        #pragma unroll
        for (int k = 0; k < 5; ++k) {
            double acc = 0.0;
            #pragma unroll
            for (int w = 0; w < NWAVES; ++w) acc += sm[k][w];
            out[k] = acc;
        }
    }
}

// One block, 256 threads: thread r reduces its row's chunk-partials,
// computes corr_r, then block-reduces the mean.
__global__ __launch_bounds__(NROWS) void finish_kernel(
        const double* __restrict__ partials, float* __restrict__ out)
{
    const int r = threadIdx.x;
    double tZ = 0, tB = 0, tZZ = 0, tBB = 0, tZB = 0;
    const double* p = partials + (long)r * CHUNKS * 5;
    #pragma unroll
    for (int c = 0; c < CHUNKS; ++c) {
        tZ  += p[c * 5 + 0];
        tB  += p[c * 5 + 1];
        tZZ += p[c * 5 + 2];
        tBB += p[c * 5 + 3];
        tZB += p[c * 5 + 4];
    }
    const double invD = 1.0 / (double)D;
    const double num  = tZB - tZ * tB * invD;
    const double varZ = fmax(tZZ - tZ * tZ * invD, 0.0);
    const double varB = fmax(tBB - tB * tB * invD, 0.0);
    const double den  = sqrt(varZ) * sqrt(varB) + EPS;
    double v = num / den;

    #pragma unroll
    for (int off = 32; off > 0; off >>= 1) v += __shfl_down(v, off);

    __shared__ double sm[NROWS / 64];
    const int wave = r >> 6;
    const int lane = r & 63;
    if (lane == 0) sm[wave] = v;
    __syncthreads();
    if (r == 0) {
        double t = 0.0;
        #pragma unroll
        for (int w = 0; w < NROWS / 64; ++w) t += sm[w];
        out[0] = (float)(t / (double)NROWS);
    }
}

extern "C" void kernel_launch(void* const* d_in, const int* in_sizes, int n_in,
                              void* d_out, int out_size, void* d_ws, size_t ws_size,
                              hipStream_t stream) {
    const f4* preds   = (const f4*)d_in[0];
    const f4* targets = (const f4*)d_in[1];
    double* partials = (double*)d_ws;   // 8192 * 5 doubles = 320 KiB
    float*  out      = (float*)d_out;

    hipLaunchKernelGGL(partial_kernel, dim3(NROWS * CHUNKS), dim3(TPB1), 0, stream,
                       preds, targets, partials);
    hipLaunchKernelGGL(finish_kernel, dim3(1), dim3(NROWS), 0, stream,
                       partials, out);
}

// Round 5
// 358.911 us; speedup vs baseline: 1.0968x; 1.0351x over previous
//
#include <hip/hip_runtime.h>
#include <stdint.h>

// PixCorr: per-row Pearson corr of preds vs targets, mean over 256 rows.
// fp32, D=3*256*256=196608/row; 402.7 MB streamed once; floor ~60-65us.
// R4 post-mortem: batched VGPR loads get flattened by the compiler to ~1-2
// outstanding dwordx4/wave (~14KB/CU in flight -> 3.8 TB/s). R5: force issue
// depth structurally with global_load_lds (no dest VGPR -> cannot be
// serialized): 8 async 16B DMAs/thread into 32KiB LDS, syncthreads (drains
// vmcnt), identity read-back, fp64 accumulate. Plus: split the single-block
// finish (latency-bound ~10-15us) into per-row reduce (256 blocks) + mean.

typedef float f4 __attribute__((ext_vector_type(4)));

constexpr int NROWS  = 256;
constexpr int D      = 3 * 256 * 256;   // 196608 floats per row
constexpr int D4     = D / 4;           // 49152 float4 per row
constexpr int TPB1   = 256;             // 4 waves per block
constexpr int BATCH  = 4;               // float4 PAIRS per thread
constexpr int C4     = TPB1 * BATCH;    // 1024 float4 per chunk
constexpr int CHUNKS = D4 / C4;         // 48 chunks per row
constexpr double EPS = 1e-6;

__device__ __forceinline__ void async_ld16(const void* g, void* l) {
    // nt cache policy (bit1) to avoid L2/L3 thrash (R3's win).
    __builtin_amdgcn_global_load_lds(
        (const __attribute__((address_space(1))) uint32_t*)g,
        (__attribute__((address_space(3))) uint32_t*)l,
        16, 0, 2);
}

// ws layout: partials[12288][5] doubles (480 KiB), then rowcorr[256] doubles.
__global__ __launch_bounds__(TPB1) void partial_kernel(
        const f4* __restrict__ preds,
        const f4* __restrict__ targets,
        double* __restrict__ partials)
{
    __shared__ f4 sBuf[2][BATCH][TPB1];   // [0]=preds(B), [1]=targets(Z); 32 KiB

    const int  blk   = blockIdx.x;
    const int  row   = blk / CHUNKS;
    const int  chunk = blk % CHUNKS;
    const int  tid   = threadIdx.x;
    const int  w     = tid >> 6;          // wave id (lane-uniform)
    const long G     = (long)row * D4 + (long)chunk * C4;

    // Issue all 8 DMAs back-to-back; LDS dest is wave-uniform base + lane*16,
    // which lands exactly at sBuf[s][u][tid] (identity mapping per thread).
    #pragma unroll
    for (int u = 0; u < BATCH; ++u) {
        const long gi = G + (long)u * TPB1 + tid;
        async_ld16(&preds[gi],   &sBuf[0][u][w * 64]);
        async_ld16(&targets[gi], &sBuf[1][u][w * 64]);
    }
    __syncthreads();   // drains vmcnt -> all DMAs landed

    double sZ = 0.0, sB = 0.0, sZZ = 0.0, sBB = 0.0, sZB = 0.0;
    #pragma unroll
    for (int u = 0; u < BATCH; ++u) {
        const f4 b4 = sBuf[0][u][tid];
        const f4 z4 = sBuf[1][u][tid];
        double z, b;
        z = (double)z4.x; b = (double)b4.x;
        sZ += z; sB += b; sZZ = fma(z,z,sZZ); sBB = fma(b,b,sBB); sZB = fma(z,b,sZB);
        z = (double)z4.y; b = (double)b4.y;
        sZ += z; sB += b; sZZ = fma(z,z,sZZ); sBB = fma(b,b,sBB); sZB = fma(z,b,sZB);
        z = (double)z4.z; b = (double)b4.z;
        sZ += z; sB += b; sZZ = fma(z,z,sZZ); sBB = fma(b,b,sBB); sZB = fma(z,b,sZB);
        z = (double)z4.w; b = (double)b4.w;
        sZ += z; sB += b; sZZ = fma(z,z,sZZ); sBB = fma(b,b,sBB); sZB = fma(z,b,sZB);
    }

    // Wave (64-lane) shuffle reduction.
    #pragma unroll
    for (int off = 32; off > 0; off >>= 1) {
        sZ  += __shfl_down(sZ,  off);
        sB  += __shfl_down(sB,  off);
        sZZ += __shfl_down(sZZ, off);
        sBB += __shfl_down(sBB, off);
        sZB += __shfl_down(sZB, off);
    }

    constexpr int NWAVES = TPB1 / 64;
    __shared__ double sm[5][NWAVES];
    const int lane = tid & 63;
    if (lane == 0) {
        sm[0][w] = sZ;  sm[1][w] = sB;
        sm[2][w] = sZZ; sm[3][w] = sBB;
        sm[4][w] = sZB;
    }
    __syncthreads();

    if (tid == 0) {
        double* out = partials + (long)blk * 5;
        #pragma unroll
        for (int k = 0; k < 5; ++k)
            out[k] = sm[k][0] + sm[k][1] + sm[k][2] + sm[k][3];
    }
}

// One block (1 wave) per row: lanes 0..47 each hold one chunk's partials,
// shuffle-reduce, lane 0 computes the row correlation.
__global__ __launch_bounds__(64) void row_reduce_kernel(
        const double* __restrict__ partials, double* __restrict__ rowcorr)
{
    const int row = blockIdx.x;
    const int c   = threadIdx.x;
    double tZ = 0, tB = 0, tZZ = 0, tBB = 0, tZB = 0;
    if (c < CHUNKS) {
        const double* p = partials + ((long)row * CHUNKS + c) * 5;
        tZ = p[0]; tB = p[1]; tZZ = p[2]; tBB = p[3]; tZB = p[4];
    }
    #pragma unroll
    for (int off = 32; off > 0; off >>= 1) {
        tZ  += __shfl_down(tZ,  off);
        tB  += __shfl_down(tB,  off);
        tZZ += __shfl_down(tZZ, off);
        tBB += __shfl_down(tBB, off);
        tZB += __shfl_down(tZB, off);
    }
    if (c == 0) {
        const double invD = 1.0 / (double)D;
        const double num  = tZB - tZ * tB * invD;
        const double varZ = fmax(tZZ - tZ * tZ * invD, 0.0);
        const double varB = fmax(tBB - tB * tB * invD, 0.0);
        const double den  = sqrt(varZ) * sqrt(varB) + EPS;
        rowcorr[row] = num / den;
    }
}

__global__ __launch_bounds__(NROWS) void mean_kernel(
        const double* __restrict__ rowcorr, float* __restrict__ out)
{
    const int tid = threadIdx.x;
    double v = rowcorr[tid];
    #pragma unroll
    for (int off = 32; off > 0; off >>= 1) v += __shfl_down(v, off);

    __shared__ double sm[NROWS / 64];
    const int wave = tid >> 6;
    const int lane = tid & 63;
    if (lane == 0) sm[wave] = v;
    __syncthreads();
    if (tid == 0) {
        double t = 0.0;
        #pragma unroll
        for (int w = 0; w < NROWS / 64; ++w) t += sm[w];
        out[0] = (float)(t / (double)NROWS);
    }
}

extern "C" void kernel_launch(void* const* d_in, const int* in_sizes, int n_in,
                              void* d_out, int out_size, void* d_ws, size_t ws_size,
                              hipStream_t stream) {
    const f4* preds   = (const f4*)d_in[0];
    const f4* targets = (const f4*)d_in[1];
    double* partials = (double*)d_ws;                        // 12288*5 doubles
    double* rowcorr  = partials + (long)NROWS * CHUNKS * 5;  // 256 doubles
    float*  out      = (float*)d_out;

    hipLaunchKernelGGL(partial_kernel, dim3(NROWS * CHUNKS), dim3(TPB1), 0, stream,
                       preds, targets, partials);
    hipLaunchKernelGGL(row_reduce_kernel, dim3(NROWS), dim3(64), 0, stream,
                       partials, rowcorr);
    hipLaunchKernelGGL(mean_kernel, dim3(1), dim3(NROWS), 0, stream,
                       rowcorr, out);
}